// Round 8
// baseline (202.078 us; speedup 1.0000x reference)
//
#include <hip/hip_runtime.h>
#include <hip/hip_bf16.h>

typedef __bf16 bf16;
typedef __bf16 bf16x8 __attribute__((ext_vector_type(8)));
typedef __bf16 bf16x4 __attribute__((ext_vector_type(4)));
typedef __bf16 bf16x2 __attribute__((ext_vector_type(2)));
typedef float f32x4 __attribute__((ext_vector_type(4)));

static __device__ __forceinline__ f32x4 mfma16(bf16x8 a, bf16x8 b, f32x4 c) {
    return __builtin_amdgcn_mfma_f32_16x16x32_bf16(a, b, c, 0, 0, 0);
}

static __device__ __forceinline__ void load16_to_lds(const void* g, void* l) {
    __builtin_amdgcn_global_load_lds(
        (const __attribute__((address_space(1))) unsigned int*)g,
        (__attribute__((address_space(3))) unsigned int*)l, 16, 0, 0);
}

#define LKV 2048
#define DM 256

// ================= shared GEMM body: Y[64 x 256] = X * W^T, W read as f32 =================
template<bool IN_BF16, bool OUT_BF16, bool HAS_BIAS>
static __device__ __forceinline__ void gemm_body(char* smem,
                                                 const void* __restrict__ Xv,
                                                 const float* __restrict__ Wf,
                                                 const float* __restrict__ bias,
                                                 float scale, void* __restrict__ Y,
                                                 long rowbase) {
    bf16* Xl  = (bf16*)smem;            // [64][264] bf16 (528B rows)
    char* WlB = smem + 33792;           // [256][40] bf16 (80B rows)
    const int tid  = threadIdx.x;
    const int lane = tid & 63, wave = tid >> 6;
    const int hi = lane >> 4, lo = lane & 15;

    if (IN_BF16) {
        const bf16* Xb = (const bf16*)Xv;
#pragma unroll
        for (int i = 0; i < 8; ++i) {
            int idx = i * 256 + tid;
            int r = idx >> 5, c8 = (idx & 31) * 8;
            uint4 v = *(const uint4*)(Xb + (rowbase + r) * 256 + c8);
            *(uint4*)(Xl + r * 264 + c8) = v;
        }
    } else {
        const float* X = (const float*)Xv;
#pragma unroll
        for (int i = 0; i < 16; ++i) {
            int idx4 = i * 256 + tid;
            int e = idx4 * 4;
            int r = e >> 8, c = e & 255;
            float4 v = *(const float4*)(X + (rowbase + r) * 256 + c);
            bf16x4 o;
            o[0] = (bf16)v.x; o[1] = (bf16)v.y; o[2] = (bf16)v.z; o[3] = (bf16)v.w;
            *(bf16x4*)(Xl + r * 264 + c) = o;
        }
    }

    f32x4 acc[16];
    const f32x4 zero = {0.f, 0.f, 0.f, 0.f};
#pragma unroll
    for (int n = 0; n < 16; ++n) acc[n] = zero;

    for (int ks = 0; ks < 8; ++ks) {
        __syncthreads();
#pragma unroll
        for (int c = 0; c < 8; ++c) {
            int idx = c * 256 + tid;            // 2048 float4 chunks
            int e = idx >> 3, q4 = (idx & 7) * 4;
            float4 v = *(const float4*)(Wf + e * 256 + ks * 32 + q4);
            bf16x4 o;
            o[0] = (bf16)v.x; o[1] = (bf16)v.y; o[2] = (bf16)v.z; o[3] = (bf16)v.w;
            *(bf16x4*)(WlB + e * 80 + q4 * 2) = o;
        }
        __syncthreads();
        bf16x8 a = *(const bf16x8*)((const char*)Xl + (wave * 16 + lo) * 528 + ks * 64 + hi * 16);
#pragma unroll
        for (int n = 0; n < 16; ++n) {
            bf16x8 bfr = *(const bf16x8*)(WlB + (n * 16 + lo) * 80 + hi * 16);
            acc[n] = mfma16(a, bfr, acc[n]);
        }
    }

#pragma unroll
    for (int n = 0; n < 16; ++n) {
        int col = n * 16 + lo;
        float bv = HAS_BIAS ? bias[col] : 0.f;
#pragma unroll
        for (int r = 0; r < 4; ++r) {
            long row = rowbase + wave * 16 + hi * 4 + r;
            float v = acc[n][r] * scale + bv;
            if (OUT_BF16) ((bf16*)Y)[row * 256 + col] = (bf16)v;
            else          ((float*)Y)[row * 256 + col] = v;
        }
    }
}

// ================= prep_qk: blocks [0,1024) = q/k projection; [1024,3072) = tsp -> tspF ======
// tspF frag layout: byte addr = b*1MB + ((t32*16 + dt)*64 + lane)*16,
// holding tspT[d = dt*16 + (lane&15)][kv = t32*32 + (lane>>4)*8 .. +7] as bf16x8.
__global__ __launch_bounds__(256) void prep_qk(const float* __restrict__ q,
                                               const float* __restrict__ k,
                                               const float* __restrict__ wqk,
                                               const float* __restrict__ tsp,
                                               bf16* __restrict__ qp,
                                               bf16* __restrict__ kp,
                                               bf16* __restrict__ tspF) {
    __shared__ __align__(16) char smem[54272];
    const int tid = threadIdx.x;
    int bid = (int)blockIdx.x;
    if (bid < 1024) {
        bool is_k = bid >= 512;
        // qp scale folds 1/temperature (1/16) AND log2e (exp2-based softmax)
        gemm_body<false, true, false>(smem, is_k ? k : q, wqk, nullptr,
                                      is_k ? 1.0f : 0.09016844f, is_k ? kp : qp,
                                      (long)(bid & 511) * 64);
        return;
    }
    int id = bid - 1024;                       // 2048 tiles: 16 b x 32 kv-tiles x 4 d-tiles
    const int b = id >> 7;
    const int kv0 = (id & 31) * 64, d0 = ((id >> 5) & 3) * 64;
    float (*tile)[65] = (float(*)[65])smem;
#pragma unroll
    for (int i = 0; i < 4; ++i) {
        int idx = i * 256 + tid;
        int kv = idx >> 4, c4 = (idx & 15) * 4;
        float4 v = *(const float4*)(tsp + ((long)(b * LKV + kv0 + kv)) * DM + d0 + c4);
        tile[kv][c4 + 0] = v.x; tile[kv][c4 + 1] = v.y;
        tile[kv][c4 + 2] = v.z; tile[kv][c4 + 3] = v.w;
    }
    __syncthreads();
    char* outb = (char*)tspF + ((long)b << 20);
#pragma unroll
    for (int i = 0; i < 2; ++i) {
        int w = i * 256 + tid;
        int ti = w >> 8;
        int dti = (w >> 6) & 3;
        int lane = w & 63;
        int hi = lane >> 4, lo = lane & 15;
        bf16x8 o;
#pragma unroll
        for (int j = 0; j < 8; ++j) o[j] = (bf16)tile[ti * 32 + hi * 8 + j][dti * 16 + lo];
        int t_abs = (kv0 >> 5) + ti;
        int dt_abs = (d0 >> 4) + dti;
        *(bf16x8*)(outb + (((t_abs * 16 + dt_abs) << 6) + lane) * 16) = o;
    }
}

// ================= gemm_out ==================================================================
__global__ __launch_bounds__(256) void gemm_out(const bf16* __restrict__ gated,
                                                const float* __restrict__ w1,
                                                const float* __restrict__ b1,
                                                float* __restrict__ out) {
    __shared__ __align__(16) char smem[54272];
    gemm_body<true, false, true>(smem, gated, w1, b1, 1.0f, out, (long)blockIdx.x * 64);
}

// ================= flash v7: 32 q-rows/wave (2 groups), cross-tile PV, counted vmcnt =========
// grid = 256 (1 block/CU), block = 256 (4 waves x 32 q). KV tile = 32, 3-slot kbuf (48KB).
// Phase t: vmcnt(N) -> barrier -> [tt(t) x16 loads, DMA kp(t+2) x4] -> QK(t) (32 MFMA)
//          || PV(t-1) (34 reg-only MFMA) -> softmax(t) -> pk.
__global__ __launch_bounds__(256, 1) void flash7(const bf16* __restrict__ qp,
                                                 const bf16* __restrict__ kp,
                                                 const bf16* __restrict__ tspF,
                                                 const float* __restrict__ qorig,
                                                 bf16* __restrict__ gated) {
    __shared__ __align__(16) char kbuf[3 * 16384];   // [kv][512B], chunk i ^= (kv&7)
    const int tid  = threadIdx.x;
    const int lane = tid & 63, wave = tid >> 6;
    const int hi = lane >> 4, lo = lane & 15;

    int id  = (int)blockIdx.x;
    int bid = (id & 7) * 32 + (id >> 3);     // 8 XCDs x 32 blocks: 2 batches per XCD
    const int b  = bid >> 4;
    const int qb = bid & 15;
    const long qbase = (long)b * LKV + qb * 128;
    const char* kp_g  = (const char*)(kp + (long)b * LKV * DM);
    const char* tsp_f = (const char*)tspF + ((long)b << 20) + lane * 16;

    int kp_off[4];
#pragma unroll
    for (int j = 0; j < 4; ++j) {
        int kv = wave * 8 + j * 2 + (lane >> 5);
        kp_off[j] = kv * 512 + (((lane & 31) ^ (kv & 7)) << 4);
    }
    int bp_src[4];
#pragma unroll
    for (int k2 = 0; k2 < 4; ++k2)
        bp_src[k2] = ((((hi & 1) * 2 + (k2 >> 1)) << 4) + lo) << 2;

    // q fragments: two 16-row groups per wave
    bf16x8 aq[2][8];
#pragma unroll
    for (int g = 0; g < 2; ++g) {
        const bf16* qrow = qp + (qbase + wave * 32 + g * 16 + lo) * DM;
#pragma unroll
        for (int ks = 0; ks < 8; ++ks) aq[g][ks] = *(const bf16x8*)(qrow + ks * 32 + hi * 8);
    }

    bf16x8 ones;
#pragma unroll
    for (int j = 0; j < 8; ++j) ones[j] = (bf16)1.0f;

    f32x4 o[2][16], o_l[2];
    const f32x4 zero = {0.f, 0.f, 0.f, 0.f};
#pragma unroll
    for (int g = 0; g < 2; ++g) { for (int n = 0; n < 16; ++n) o[g][n] = zero; o_l[g] = zero; }
    float m[2] = {-1e30f, -1e30f}, tm[2] = {-1e30f, -1e30f};
    bf16x8 pk[2];
    bf16x8 tt0[16], tt1[16];

    const int kswz = (lo & 7) << 4;

    // prologue: DMA kp tiles 0,1 into slots 0,1
#pragma unroll
    for (int j = 0; j < 4; ++j)
        load16_to_lds(kp_g + kp_off[j],          kbuf + wave * 4096 + j * 1024);
#pragma unroll
    for (int j = 0; j < 4; ++j)
        load16_to_lds(kp_g + 16384 + kp_off[j],  kbuf + 16384 + wave * 4096 + j * 1024);

#define SOFTMAX_PK()                                                              \
    {                                                                             \
        float pm[2];                                                              \
        _Pragma("unroll")                                                         \
        for (int g = 0; g < 2; ++g) {                                             \
            float v = fmaxf(fmaxf(fmaxf(s[g][0][0], s[g][0][1]),                  \
                                  fmaxf(s[g][0][2], s[g][0][3])),                 \
                            fmaxf(fmaxf(s[g][1][0], s[g][1][1]),                  \
                                  fmaxf(s[g][1][2], s[g][1][3])));                \
            v = fmaxf(v, __shfl_xor(v, 16));                                      \
            v = fmaxf(v, __shfl_xor(v, 32));                                      \
            pm[g] = v;                                                            \
            tm[g] = fmaxf(tm[g], v);                                              \
        }                                                                         \
        bool need = (pm[0] > m[0] + 11.5f) || (pm[1] > m[1] + 11.5f);             \
        if (__any(need)) {                                                        \
            _Pragma("unroll")                                                     \
            for (int g = 0; g < 2; ++g) {                                         \
                float nm = fmaxf(m[g], pm[g]);                                    \
                float a = exp2f(m[g] - nm);                                       \
                m[g] = nm;                                                        \
                o_l[g] *= a;                                                      \
                _Pragma("unroll")                                                 \
                for (int n = 0; n < 16; ++n) o[g][n] *= a;                        \
            }                                                                     \
        }                                                                         \
        _Pragma("unroll")                                                         \
        for (int g = 0; g < 2; ++g) {                                             \
            int cvt[2][2];                                                        \
            _Pragma("unroll")                                                     \
            for (int n = 0; n < 2; ++n)                                           \
                _Pragma("unroll")                                                 \
                for (int c = 0; c < 2; ++c) {                                     \
                    bf16x2 pr;                                                    \
                    pr[0] = (bf16)exp2f(s[g][n][2 * c]     - m[g]);               \
                    pr[1] = (bf16)exp2f(s[g][n][2 * c + 1] - m[g]);               \
                    cvt[n][c] = __builtin_bit_cast(int, pr);                      \
                }                                                                 \
            int pki[4];                                                           \
            _Pragma("unroll")                                                     \
            for (int k2 = 0; k2 < 4; ++k2) {                                      \
                int a0 = __builtin_amdgcn_ds_bpermute(bp_src[k2], cvt[0][k2 & 1]);\
                int a1 = __builtin_amdgcn_ds_bpermute(bp_src[k2], cvt[1][k2 & 1]);\
                pki[k2] = (hi < 2) ? a0 : a1;                                     \
            }                                                                     \
            int4 pii = make_int4(pki[0], pki[1], pki[2], pki[3]);                 \
            pk[g] = __builtin_bit_cast(bf16x8, pii);                              \
        }                                                                         \
    }

#define PHASE(T, VMN, TTN, TTO, DO_PV, DO_DMA)                                    \
    {                                                                             \
        asm volatile("s_waitcnt vmcnt(" #VMN ")" ::: "memory");                   \
        __builtin_amdgcn_sched_barrier(0);                                        \
        __builtin_amdgcn_s_barrier();                                             \
        __builtin_amdgcn_sched_barrier(0);                                        \
        {                                                                         \
            const char* tb = tsp_f + (long)(T) * 16384;                           \
            _Pragma("unroll")                                                     \
            for (int dt = 0; dt < 16; ++dt)                                       \
                TTN[dt] = *(const bf16x8*)(tb + dt * 1024);                       \
        }                                                                         \
        if (DO_DMA) {                                                             \
            const char* src = kp_g + (long)((T) + 2) * 16384;                     \
            char* dst = kbuf + (((T) + 2) % 3) * 16384 + wave * 4096;             \
            _Pragma("unroll")                                                     \
            for (int j = 0; j < 4; ++j)                                           \
                load16_to_lds(src + kp_off[j], dst + j * 1024);                   \
        }                                                                         \
        f32x4 s[2][2];                                                            \
        s[0][0] = zero; s[0][1] = zero; s[1][0] = zero; s[1][1] = zero;           \
        {                                                                         \
            const char* kb = kbuf + ((T) % 3) * 16384;                            \
            __builtin_amdgcn_s_setprio(1);                                        \
            _Pragma("unroll")                                                     \
            for (int n = 0; n < 2; ++n) {                                         \
                const char* rowp = kb + ((n * 16 + lo) << 9);                     \
                _Pragma("unroll")                                                 \
                for (int ks = 0; ks < 8; ++ks) {                                  \
                    bf16x8 kk = *(const bf16x8*)(rowp + ((ks * 64 + hi * 16) ^ kswz)); \
                    s[0][n] = mfma16(kk, aq[0][ks], s[0][n]);                     \
                    s[1][n] = mfma16(kk, aq[1][ks], s[1][n]);                     \
                }                                                                 \
            }                                                                     \
            if (DO_PV) {                                                          \
                o_l[0] = mfma16(ones, pk[0], o_l[0]);                             \
                o_l[1] = mfma16(ones, pk[1], o_l[1]);                             \
                _Pragma("unroll")                                                 \
                for (int dt = 0; dt < 16; ++dt) {                                 \
                    o[0][dt] = mfma16(TTO[dt], pk[0], o[0][dt]);                  \
                    o[1][dt] = mfma16(TTO[dt], pk[1], o[1][dt]);                  \
                }                                                                 \
            }                                                                     \
            __builtin_amdgcn_s_setprio(0);                                        \
        }                                                                         \
        SOFTMAX_PK();                                                             \
    }

    // phase 0 (no PV), then steady pairs, then phase 63 (no DMA), then tail PV(63)
    PHASE(0, 8, tt0, tt1, false, true)
    for (int t = 1; t < 63; t += 2) {
        PHASE(t,     24, tt1, tt0, true, (t     < 62))
        PHASE(t + 1, 24, tt0, tt1, true, (t + 1 < 62))
    }
    PHASE(63, 16, tt1, tt0, true, false)
    {
        o_l[0] = mfma16(ones, pk[0], o_l[0]);
        o_l[1] = mfma16(ones, pk[1], o_l[1]);
#pragma unroll
        for (int dt = 0; dt < 16; ++dt) {
            o[0][dt] = mfma16(tt1[dt], pk[0], o[0][dt]);
            o[1][dt] = mfma16(tt1[dt], pk[1], o[1][dt]);
        }
    }

    // ---- epilogue: group g, lane owns q-row lo; d = dt*16 + 4*hi + r ----
#pragma unroll
    for (int g = 0; g < 2; ++g) {
        float prob = 1.f / (1.f + __expf(-tm[g] * 0.69314718f));
        float invl = 1.f / o_l[g][0];
        long row = qbase + wave * 32 + g * 16 + lo;
#pragma unroll
        for (int dt = 0; dt < 16; ++dt) {
            int c0 = dt * 16 + hi * 4;
            float4 qv = *(const float4*)(qorig + row * 256 + c0);
            bf16x4 gg;
            gg[0] = (bf16)((qv.x + o[g][dt][0] * invl) * prob);
            gg[1] = (bf16)((qv.y + o[g][dt][1] * invl) * prob);
            gg[2] = (bf16)((qv.z + o[g][dt][2] * invl) * prob);
            gg[3] = (bf16)((qv.w + o[g][dt][3] * invl) * prob);
            *(bf16x4*)(gated + row * 256 + c0) = gg;
        }
    }
#undef PHASE
#undef SOFTMAX_PK
}

extern "C" void kernel_launch(void* const* d_in, const int* in_sizes, int n_in,
                              void* d_out, int out_size, void* d_ws, size_t ws_size,
                              hipStream_t stream) {
    const float* q    = (const float*)d_in[0];
    const float* k    = (const float*)d_in[1];
    const float* tsp  = (const float*)d_in[2];
    const float* w_qk = (const float*)d_in[3];
    const float* w1   = (const float*)d_in[4];
    const float* b1   = (const float*)d_in[5];
    float* out = (float*)d_out;
    char* ws = (char*)d_ws;

    bf16* qp_b  = (bf16*)(ws + 0);           // 16 MB
    bf16* kp_b  = (bf16*)(ws + 16777216);    // 16 MB
    bf16* tspF  = (bf16*)(ws + 33554432);    // 16 MB (frag layout)
    bf16* gated = (bf16*)(ws + 50331648);    // 16 MB

    prep_qk<<<3072, 256, 0, stream>>>(q, k, w_qk, tsp, qp_b, kp_b, tspF);

    flash7<<<256, 256, 0, stream>>>(qp_b, kp_b, tspF, q, gated);

    gemm_out<<<512, 256, 0, stream>>>(gated, w1, b1, out);
}